// Round 13
// baseline (184.146 us; speedup 1.0000x reference)
//
#include <hip/hip_runtime.h>
#include <hip/hip_bf16.h>
#include <math.h>

// Problem constants (fixed by the reference)
constexpr int Bn = 32768;   // batch
constexpr int Dn = 256;     // embedding dim
constexpr int Cn = 2048;    // classes
constexpr int NSPLIT = 4;               // class splits in k_main (R9-verified best)
constexpr int CLS_PER_BLK = Cn / NSPLIT; // 512
constexpr int TCLS = 32;                 // classes per staged tile (VERIFIED; 64 spills)
constexpr int NIT = CLS_PER_BLK / TCLS;  // 16 staged tiles per block
#define EPSF 1e-12f
#define INFF __builtin_inff()

typedef __bf16 bf16x8 __attribute__((ext_vector_type(8)));
typedef __bf16 bf16x4 __attribute__((ext_vector_type(4)));
typedef float  f32x4  __attribute__((ext_vector_type(4)));

__device__ inline void async_copy16(const void* g, void* l) {
    __builtin_amdgcn_global_load_lds(
        (const __attribute__((address_space(1))) void*)g,
        (__attribute__((address_space(3))) void*)l, 16, 0, 0);
}

// ---------------- K1: normalize, prescale by -2, store bf16 ---------------
// wave per sample; lane covers 4 dims. fneg[i] = -2 * f_i (bf16).
// Pure streaming (hist pipeline deleted — see k_centseg ballot scan).
__global__ __launch_bounds__(256) void k_prep(const float* __restrict__ feat,
                                              __bf16* __restrict__ fneg) {
    const int wave = threadIdx.x >> 6, lane = threadIdx.x & 63;
    const int s = blockIdx.x * 4 + wave;
    const float4 v = ((const float4*)(feat + (size_t)s * Dn))[lane];
    float ss = v.x * v.x + v.y * v.y + v.z * v.z + v.w * v.w;
    #pragma unroll
    for (int off = 1; off < 64; off <<= 1) ss += __shfl_xor(ss, off, 64);
    const float inv = -2.0f / fmaxf(sqrtf(ss), EPSF);
    bf16x4 bf;
    bf[0] = (__bf16)(v.x * inv); bf[1] = (__bf16)(v.y * inv);
    bf[2] = (__bf16)(v.z * inv); bf[3] = (__bf16)(v.w * inv);
    *(bf16x4*)(fneg + (size_t)s * Dn + lane * 4) = bf;
}

// ---------------- K2: ballot-scan centroids -> centK + cn2 + cnt_i --------
// Replaces {memset(hist), hist-atomics, k_scan, k_scatter, order[]} — the
// whole sort pipeline (3 graph nodes + memset, ~6.5us/node overhead each).
// One class per wave; the wave scans ALL labels (128KB, L2-resident) in
// int4 chunks with wave-wide ballots, gathering matching fneg rows
// (coalesced 512B per match). cnt from popcount. All intra-block; no
// cross-block coordination. Block 0 zeroes accum/donecnt for k_final
// (stream order guarantees completion before k_final).
__global__ __launch_bounds__(256) void k_centseg(const __bf16* __restrict__ fneg,
                                                 const int* __restrict__ labels,
                                                 int* __restrict__ cnt_i,
                                                 __bf16* __restrict__ centK,
                                                 float* __restrict__ cn2x,
                                                 float* __restrict__ accum,
                                                 unsigned* __restrict__ donecnt) {
    const int wave = threadIdx.x >> 6, lane = threadIdx.x & 63;
    const int c = blockIdx.x * 4 + wave;
    if (blockIdx.x == 0 && threadIdx.x == 0) {
        accum[0] = 0.f; accum[1] = 0.f; *donecnt = 0u;
    }
    float sx = 0.f, sy = 0.f, sz = 0.f, sw = 0.f;
    int cnt = 0;
    const int4* lab4 = (const int4*)labels;
    for (int ch = 0; ch < Bn / 256; ++ch) {         // 128 iterations
        const int4 l4 = lab4[ch * 64 + lane];       // lane holds samples ch*256+4*lane+{0..3}
        unsigned long long b0 = __ballot(l4.x == c);
        unsigned long long b1 = __ballot(l4.y == c);
        unsigned long long b2 = __ballot(l4.z == c);
        unsigned long long b3 = __ballot(l4.w == c);
        cnt += __popcll(b0) + __popcll(b1) + __popcll(b2) + __popcll(b3);
        const int base = ch * 256;
        // enumerate matches (ballots are wave-uniform -> uniform loops)
        #pragma unroll
        for (int w = 0; w < 4; ++w) {
            unsigned long long b = (w == 0) ? b0 : (w == 1) ? b1 : (w == 2) ? b2 : b3;
            while (b) {
                const int s = __ffsll(b) - 1; b &= b - 1;
                const int idx = base + 4 * s + w;
                const bf16x4 v = *(const bf16x4*)(fneg + (size_t)idx * Dn + lane * 4);
                sx += -0.5f * (float)v[0]; sy += -0.5f * (float)v[1];
                sz += -0.5f * (float)v[2]; sw += -0.5f * (float)v[3];
            }
        }
    }
    const int n = cnt;
    const float invn = 1.0f / fmaxf((float)n, 1.0f);
    const float cx = sx * invn, cy = sy * invn, cz = sz * invn, cw = sw * invn;
    // centK chunk (kc, c): dims [8kc, 8kc+8); lane covers kc = lane>>1, half lane&1
    bf16x4 cb; cb[0] = (__bf16)cx; cb[1] = (__bf16)cy; cb[2] = (__bf16)cz; cb[3] = (__bf16)cw;
    *(bf16x4*)(centK + ((size_t)(lane >> 1) * Cn + c) * 8 + (lane & 1) * 4) = cb;
    float ss = cx * cx + cy * cy + cz * cz + cw * cw;
    #pragma unroll
    for (int off = 1; off < 64; off <<= 1) ss += __shfl_xor(ss, off, 64);
    if (lane == 0) {
        cn2x[c] = (n > 0) ? ss : INFF;
        cnt_i[c] = n;
    }
}

// ---------------- K5: MFMA dot + masked min + own-class dot extraction ----
// EXACT R9-verified kernel (50us, 120 VGPR, no spill; best total 161.05).
// Closed: TCLS=64 spilled (R8), (256,4) spilled (R5), counted-vmcnt
// regressed (R4), NSPLIT=8 regressed (R10), epilogue trim neutral (R12 —
// VALU 27.8->16.5% with flat time => latency/barrier-bound, not VALU).
// A = -2f (prescaled), so cn2 + acc = cn2 - 2*dot = d^2 - 1.
__global__ __launch_bounds__(256, 2) void k_main(const __bf16* __restrict__ fneg,
                                                 const int* __restrict__ labels,
                                                 const __bf16* __restrict__ centK,
                                                 const float* __restrict__ cn2x,
                                                 float* __restrict__ minval,
                                                 float* __restrict__ dotown) {
    __shared__ __align__(16) __bf16 sB[2][TCLS * Dn];  // 2 x 16KB class tiles
    __shared__ float s_cn2[CLS_PER_BLK];               // 2KB
    const int lane = threadIdx.x & 63, wave = threadIdx.x >> 6;
    const int m16 = lane & 15, quad = lane >> 4;
    const int sbase = blockIdx.x * 256 + wave * 64;
    const int c_begin = blockIdx.y * CLS_PER_BLK;

    // A fragments: a[p][t] = fneg[sbase+16p+m16][32t+8*quad .. +7]
    bf16x8 a[4][8];
    #pragma unroll
    for (int p = 0; p < 4; ++p) {
        const __bf16* fr = fneg + (size_t)(sbase + p * 16 + m16) * Dn + quad * 8;
        #pragma unroll
        for (int t = 0; t < 8; ++t) a[p][t] = *(const bf16x8*)(fr + t * 32);
    }
    int lab[4][4];
    #pragma unroll
    for (int p = 0; p < 4; ++p)
        #pragma unroll
        for (int r = 0; r < 4; ++r)
            lab[p][r] = labels[sbase + p * 16 + quad * 4 + r];

    float rm[4][4], dacc[4][4];
    #pragma unroll
    for (int p = 0; p < 4; ++p)
        #pragma unroll
        for (int r = 0; r < 4; ++r) { rm[p][r] = INFF; dacc[p][r] = 0.0f; }

    // stage class-tile `it` (32 classes, 16KB) into sB[buf]:
    // LDS layout: half h (16 classes) at element h*4096; within half,
    // chunk (kc, n) at element (kc*16+n)*8  (16B per chunk, linear in chunk id)
    auto stage = [&](int buf, int it) {
        const int c0 = c_begin + it * TCLS;
        #pragma unroll
        for (int j = 0; j < 4; ++j) {
            const int chunk = wave * 256 + j * 64 + lane;     // 0..1023
            const int h  = chunk >> 9;                        // half 0/1
            const int kc = (chunk >> 4) & 31;                 // k-chunk 0..31
            const int n  = chunk & 15;                        // class-in-half
            const __bf16* g = centK + ((size_t)kc * Cn + (c0 + h * 16 + n)) * 8;
            __bf16* l = &sB[buf][(size_t)(wave * 256 + j * 64) * 8]; // wave-uniform
            async_copy16(g, l);
        }
    };

    stage(0, 0);
    for (int c = threadIdx.x; c < CLS_PER_BLK; c += 256) s_cn2[c] = cn2x[c_begin + c];
    __syncthreads();
    for (int it = 0; it < NIT; ++it) {
        const int cur = it & 1;
        if (it + 1 < NIT) stage(cur ^ 1, it + 1);
        #pragma unroll
        for (int hh = 0; hh < 2; ++hh) {
            const int ctile = it * TCLS + hh * 16;
            const float cn2v = s_cn2[ctile + m16];
            const __bf16* ls = &sB[cur][hh * 4096];
            f32x4 acc[4] = {{0.f,0.f,0.f,0.f},{0.f,0.f,0.f,0.f},
                            {0.f,0.f,0.f,0.f},{0.f,0.f,0.f,0.f}};
            #pragma unroll
            for (int t = 0; t < 8; ++t) {
                const bf16x8 b = *(const bf16x8*)(ls + t * 512 + lane * 8); // conflict-free
                #pragma unroll
                for (int p = 0; p < 4; ++p)
                    acc[p] = __builtin_amdgcn_mfma_f32_16x16x32_bf16(a[p][t], b, acc[p], 0, 0, 0);
            }
            const int crow = c_begin + ctile + m16;
            #pragma unroll
            for (int p = 0; p < 4; ++p)
                #pragma unroll
                for (int r = 0; r < 4; ++r) {
                    const bool own = (crow == lab[p][r]);
                    const float sel = own ? INFF : cn2v;
                    rm[p][r] = fminf(rm[p][r], sel + acc[p][r]);
                    dacc[p][r] += own ? acc[p][r] : 0.0f;
                }
        }
        __syncthreads();
    }
    #pragma unroll
    for (int off = 1; off < 16; off <<= 1)
        #pragma unroll
        for (int p = 0; p < 4; ++p)
            #pragma unroll
            for (int r = 0; r < 4; ++r) {
                rm[p][r] = fminf(rm[p][r], __shfl_xor(rm[p][r], off, 64));
                dacc[p][r] += __shfl_xor(dacc[p][r], off, 64);
            }
    if (m16 == 0) {
        float* mv = minval + (size_t)blockIdx.y * Bn;
        float* dv = dotown + (size_t)blockIdx.y * Bn;
        #pragma unroll
        for (int p = 0; p < 4; ++p)
            #pragma unroll
            for (int r = 0; r < 4; ++r) {
                mv[sbase + p * 16 + quad * 4 + r] = rm[p][r];
                dv[sbase + p * 16 + quad * 4 + r] = dacc[p][r];
            }
    }
}

// ---------------- K6: d_p, d_n, softplus, reduce + last-block finalize ----
// EXACT R9-verified form.
__global__ __launch_bounds__(256) void k_final(const int* __restrict__ labels,
                                               const int* __restrict__ cnt_i,
                                               const float* __restrict__ cn2x,
                                               const float* __restrict__ minval,
                                               const float* __restrict__ dotown,
                                               const int* __restrict__ epoch,
                                               float* __restrict__ accum,
                                               unsigned* __restrict__ donecnt,
                                               float* __restrict__ out) {
    const int i = blockIdx.x * 256 + threadIdx.x;
    const int lane = threadIdx.x & 63;
    const float temp = fminf(0.3f + 0.02f * (float)(*epoch), 1.0f);
    float m = minval[i];
    float draw = dotown[i];                 // = -2 * f.c_own (one split nonzero)
    #pragma unroll
    for (int k = 1; k < NSPLIT; ++k) {
        m = fminf(m, minval[(size_t)k * Bn + i]);
        draw += dotown[(size_t)k * Bn + i];
    }
    const int l = labels[i];
    const int n = cnt_i[l];
    const float nf = (float)n;
    const float cn2 = cn2x[l];              // finite (n >= 1)
    // d_p from ||f||^2=1, f.s = n*f.c, ||s||^2 = n^2*cn2:
    const float fds = nf * (-0.5f * draw);
    const float fm1 = fmaxf(nf - 1.0f, 1.0f);
    const float fdcp = (fds - 1.0f) / fm1;
    const float cp2 = (nf * nf * cn2 - 2.0f * fds + 1.0f) / (fm1 * fm1);
    const float dp2 = 1.0f - 2.0f * fdcp + cp2;
    const float d_p = sqrtf(fmaxf(dp2, 0.0f) + EPSF);
    const bool finite = (m < 1e37f);
    const float d_n = finite ? sqrtf(fmaxf(1.0f + m, EPSF)) : 0.0f;
    const bool valid = (n > 1) && finite;
    const float x = (d_p - d_n) / temp;
    const float sp = fmaxf(x, 0.0f) + log1pf(expf(-fabsf(x)));
    float ws = valid ? sp : 0.0f, wc = valid ? 1.0f : 0.0f;
    #pragma unroll
    for (int off = 1; off < 64; off <<= 1) {
        ws += __shfl_xor(ws, off, 64);
        wc += __shfl_xor(wc, off, 64);
    }
    if (lane == 0) {
        atomicAdd(&accum[0], ws);
        atomicAdd(&accum[1], wc);
        __threadfence();   // release: my adds visible before donecnt bump
    }
    __syncthreads();
    if (threadIdx.x == 0) {
        const unsigned old = atomicAdd(donecnt, 1u);
        if (old == (unsigned)(gridDim.x - 1)) {   // last block finalizes
            __threadfence();   // acquire
            const float s = __hip_atomic_load(&accum[0], __ATOMIC_RELAXED,
                                              __HIP_MEMORY_SCOPE_AGENT);
            const float c = __hip_atomic_load(&accum[1], __ATOMIC_RELAXED,
                                              __HIP_MEMORY_SCOPE_AGENT);
            out[0] = (c > 0.0f) ? (s / fmaxf(c, 1.0f)) : 0.0f;   // WEIGHT = 1.0
        }
    }
}

// ---------------- launch ---------------------------------------------------
// Graph: 4 nodes (was 7): prep, centseg(ballot), main, final. No memsets.
extern "C" void kernel_launch(void* const* d_in, const int* in_sizes, int n_in,
                              void* d_out, int out_size, void* d_ws, size_t ws_size,
                              hipStream_t stream) {
    const float* feat  = (const float*)d_in[0];
    const int* labels  = (const int*)d_in[1];
    const int* epoch   = (const int*)d_in[2];
    float* out = (float*)d_out;
    char* ws = (char*)d_ws;

    size_t off = 0;
    __bf16* fneg     = (__bf16*)(ws + off); off += (size_t)Bn * Dn * 2;     // 16 MiB
    __bf16* centK    = (__bf16*)(ws + off); off += (size_t)Cn * Dn * 2;     //  1 MiB
    float*  cn2x     = (float*)(ws + off);  off += (size_t)Cn * 4;
    int*    cnt_i    = (int*)(ws + off);    off += (size_t)Cn * 4;
    float*  minval   = (float*)(ws + off);  off += (size_t)NSPLIT * Bn * 4;
    float*  dotown   = (float*)(ws + off);  off += (size_t)NSPLIT * Bn * 4;
    float*  accum    = (float*)(ws + off);  off += 2 * 4;
    unsigned* donecnt = (unsigned*)(ws + off); off += 4;

    k_prep<<<Bn / 4, 256, 0, stream>>>(feat, fneg);
    k_centseg<<<Cn / 4, 256, 0, stream>>>(fneg, labels, cnt_i, centK, cn2x,
                                          accum, donecnt);
    dim3 g5(Bn / 256, NSPLIT);
    k_main<<<g5, 256, 0, stream>>>(fneg, labels, centK, cn2x, minval, dotown);
    k_final<<<Bn / 256, 256, 0, stream>>>(labels, cnt_i, cn2x, minval, dotown,
                                          epoch, accum, donecnt, out);
}

// Round 15
// 160.741 us; speedup vs baseline: 1.1456x; 1.1456x over previous
//
#include <hip/hip_runtime.h>
#include <hip/hip_bf16.h>
#include <math.h>

// Problem constants (fixed by the reference)
constexpr int Bn = 32768;   // batch
constexpr int Dn = 256;     // embedding dim
constexpr int Cn = 2048;    // classes
constexpr int NSPLIT = 4;               // class splits in k_main (verified best)
constexpr int CLS_PER_BLK = Cn / NSPLIT; // 512
constexpr int TCLS = 32;                 // classes per staged tile (VERIFIED; 64 spills)
constexpr int NIT = CLS_PER_BLK / TCLS;  // 16 staged tiles per block
#define EPSF 1e-12f
#define INFF __builtin_inff()

typedef __bf16 bf16x8 __attribute__((ext_vector_type(8)));
typedef __bf16 bf16x4 __attribute__((ext_vector_type(4)));
typedef float  f32x4  __attribute__((ext_vector_type(4)));

__device__ inline void async_copy16(const void* g, void* l) {
    __builtin_amdgcn_global_load_lds(
        (const __attribute__((address_space(1))) void*)g,
        (__attribute__((address_space(3))) void*)l, 16, 0, 0);
}

// ---------------- K1: normalize, prescale by -2, store bf16; + histogram --
// wave per sample; lane covers 4 dims. fneg[i] = -2 * f_i (bf16).
// Hist atomics hidden under the memory-bound prep (R1/R9-verified; moving
// them to a serial kernel cost ~10us in R7, ballot-scan cost ~57us in R13).
__global__ __launch_bounds__(256) void k_prep(const float* __restrict__ feat,
                                              const int* __restrict__ labels,
                                              __bf16* __restrict__ fneg,
                                              int* __restrict__ hist) {
    const int wave = threadIdx.x >> 6, lane = threadIdx.x & 63;
    const int s = blockIdx.x * 4 + wave;
    const float4 v = ((const float4*)(feat + (size_t)s * Dn))[lane];
    float ss = v.x * v.x + v.y * v.y + v.z * v.z + v.w * v.w;
    #pragma unroll
    for (int off = 1; off < 64; off <<= 1) ss += __shfl_xor(ss, off, 64);
    const float inv = -2.0f / fmaxf(sqrtf(ss), EPSF);
    bf16x4 bf;
    bf[0] = (__bf16)(v.x * inv); bf[1] = (__bf16)(v.y * inv);
    bf[2] = (__bf16)(v.z * inv); bf[3] = (__bf16)(v.w * inv);
    *(bf16x4*)(fneg + (size_t)s * Dn + lane * 4) = bf;
    if (lane == 0) atomicAdd(&hist[labels[s]], 1);
}

// ---------------- K2: exclusive scan of 2048-bin histogram (1 tiny block) -
// Also zeroes accum/donecnt (folds away the accum memset node).
__global__ __launch_bounds__(256) void k_scan(const int* __restrict__ hist,
                                              int* __restrict__ cnt_i,
                                              int* __restrict__ offs,
                                              int* __restrict__ offs_work,
                                              float* __restrict__ accum,
                                              unsigned* __restrict__ donecnt) {
    __shared__ int part[256];
    const int t = threadIdx.x;
    if (t == 0) { accum[0] = 0.f; accum[1] = 0.f; *donecnt = 0u; }
    int h[8], pre[8]; int sum = 0;
    #pragma unroll
    for (int j = 0; j < 8; ++j) { h[j] = hist[t * 8 + j]; pre[j] = sum; sum += h[j]; }
    int v = sum;
    part[t] = v; __syncthreads();
    for (int off = 1; off < 256; off <<= 1) {
        int add = (t >= off) ? part[t - off] : 0;
        __syncthreads();
        v += add; part[t] = v;
        __syncthreads();
    }
    const int base = v - sum;   // exclusive prefix of this thread's 8 bins
    #pragma unroll
    for (int j = 0; j < 8; ++j) {
        const int b = t * 8 + j, o = base + pre[j];
        cnt_i[b] = h[j]; offs[b] = o; offs_work[b] = o;
    }
}

// ---------------- K3: scatter sample indices by class (distributed) -------
__global__ __launch_bounds__(256) void k_scatter(const int* __restrict__ labels,
                                                 int* __restrict__ offs_work,
                                                 int* __restrict__ order) {
    const int i = blockIdx.x * 256 + threadIdx.x;
    const int pos = atomicAdd(&offs_work[labels[i]], 1);
    order[pos] = i;
}

// ---------------- K4: per-class sums -> centK (K-major bf16) + cn2 --------
// wave per class; lane covers 4 dims. fneg holds -2f; scale by -0.5.
__global__ __launch_bounds__(256) void k_centseg(const __bf16* __restrict__ fneg,
                                                 const int* __restrict__ order,
                                                 const int* __restrict__ offs,
                                                 const int* __restrict__ cnt_i,
                                                 __bf16* __restrict__ centK,
                                                 float* __restrict__ cn2x) {
    const int wave = threadIdx.x >> 6, lane = threadIdx.x & 63;
    const int c = blockIdx.x * 4 + wave;
    const int n = cnt_i[c], start = offs[c];
    int myidx = 0;
    if (lane < n) myidx = order[start + lane];
    float sx = 0.f, sy = 0.f, sz = 0.f, sw = 0.f;
    const int nf = (n < 64) ? n : 64;
    for (int j = 0; j < nf; ++j) {
        const int idx = __shfl(myidx, j, 64);
        const bf16x4 v = *(const bf16x4*)(fneg + (size_t)idx * Dn + lane * 4);
        sx += -0.5f * (float)v[0]; sy += -0.5f * (float)v[1];
        sz += -0.5f * (float)v[2]; sw += -0.5f * (float)v[3];
    }
    for (int j = 64; j < n; ++j) {          // overflow fallback (rare)
        const int idx = order[start + j];
        const bf16x4 v = *(const bf16x4*)(fneg + (size_t)idx * Dn + lane * 4);
        sx += -0.5f * (float)v[0]; sy += -0.5f * (float)v[1];
        sz += -0.5f * (float)v[2]; sw += -0.5f * (float)v[3];
    }
    const float invn = 1.0f / fmaxf((float)n, 1.0f);
    const float cx = sx * invn, cy = sy * invn, cz = sz * invn, cw = sw * invn;
    // centK chunk (kc, c): dims [8kc, 8kc+8); lane covers kc = lane>>1, half lane&1
    bf16x4 cb; cb[0] = (__bf16)cx; cb[1] = (__bf16)cy; cb[2] = (__bf16)cz; cb[3] = (__bf16)cw;
    *(bf16x4*)(centK + ((size_t)(lane >> 1) * Cn + c) * 8 + (lane & 1) * 4) = cb;
    float ss = cx * cx + cy * cy + cz * cz + cw * cw;
    #pragma unroll
    for (int off = 1; off < 64; off <<= 1) ss += __shfl_xor(ss, off, 64);
    if (lane == 0) cn2x[c] = (n > 0) ? ss : INFF;
}

// ---------------- K5: MFMA dot + masked min + own-class dot extraction ----
// EXACT R9-verified kernel (~50us, 120 VGPR, no spill; best total 161.05).
// Closed by falsification: TCLS=64 spilled (R8); (256,4) spilled (R5);
// counted-vmcnt graft regressed (R4); coop fusion regressed (R3); NSPLIT=8
// regressed (R10); epilogue-VALU trim neutral (R12: VALUBusy 27.8->16.5%
// with flat time => latency/barrier-bound under this sync structure).
// A = -2f (prescaled), so cn2 + acc = cn2 - 2*dot = d^2 - 1.
__global__ __launch_bounds__(256, 2) void k_main(const __bf16* __restrict__ fneg,
                                                 const int* __restrict__ labels,
                                                 const __bf16* __restrict__ centK,
                                                 const float* __restrict__ cn2x,
                                                 float* __restrict__ minval,
                                                 float* __restrict__ dotown) {
    __shared__ __align__(16) __bf16 sB[2][TCLS * Dn];  // 2 x 16KB class tiles
    __shared__ float s_cn2[CLS_PER_BLK];               // 2KB
    const int lane = threadIdx.x & 63, wave = threadIdx.x >> 6;
    const int m16 = lane & 15, quad = lane >> 4;
    const int sbase = blockIdx.x * 256 + wave * 64;
    const int c_begin = blockIdx.y * CLS_PER_BLK;

    // A fragments: a[p][t] = fneg[sbase+16p+m16][32t+8*quad .. +7]
    bf16x8 a[4][8];
    #pragma unroll
    for (int p = 0; p < 4; ++p) {
        const __bf16* fr = fneg + (size_t)(sbase + p * 16 + m16) * Dn + quad * 8;
        #pragma unroll
        for (int t = 0; t < 8; ++t) a[p][t] = *(const bf16x8*)(fr + t * 32);
    }
    int lab[4][4];
    #pragma unroll
    for (int p = 0; p < 4; ++p)
        #pragma unroll
        for (int r = 0; r < 4; ++r)
            lab[p][r] = labels[sbase + p * 16 + quad * 4 + r];

    float rm[4][4], dacc[4][4];
    #pragma unroll
    for (int p = 0; p < 4; ++p)
        #pragma unroll
        for (int r = 0; r < 4; ++r) { rm[p][r] = INFF; dacc[p][r] = 0.0f; }

    // stage class-tile `it` (32 classes, 16KB) into sB[buf]:
    // LDS layout: half h (16 classes) at element h*4096; within half,
    // chunk (kc, n) at element (kc*16+n)*8  (16B per chunk, linear in chunk id)
    auto stage = [&](int buf, int it) {
        const int c0 = c_begin + it * TCLS;
        #pragma unroll
        for (int j = 0; j < 4; ++j) {
            const int chunk = wave * 256 + j * 64 + lane;     // 0..1023
            const int h  = chunk >> 9;                        // half 0/1
            const int kc = (chunk >> 4) & 31;                 // k-chunk 0..31
            const int n  = chunk & 15;                        // class-in-half
            const __bf16* g = centK + ((size_t)kc * Cn + (c0 + h * 16 + n)) * 8;
            __bf16* l = &sB[buf][(size_t)(wave * 256 + j * 64) * 8]; // wave-uniform
            async_copy16(g, l);
        }
    };

    stage(0, 0);
    for (int c = threadIdx.x; c < CLS_PER_BLK; c += 256) s_cn2[c] = cn2x[c_begin + c];
    __syncthreads();
    for (int it = 0; it < NIT; ++it) {
        const int cur = it & 1;
        if (it + 1 < NIT) stage(cur ^ 1, it + 1);
        #pragma unroll
        for (int hh = 0; hh < 2; ++hh) {
            const int ctile = it * TCLS + hh * 16;
            const float cn2v = s_cn2[ctile + m16];
            const __bf16* ls = &sB[cur][hh * 4096];
            f32x4 acc[4] = {{0.f,0.f,0.f,0.f},{0.f,0.f,0.f,0.f},
                            {0.f,0.f,0.f,0.f},{0.f,0.f,0.f,0.f}};
            #pragma unroll
            for (int t = 0; t < 8; ++t) {
                const bf16x8 b = *(const bf16x8*)(ls + t * 512 + lane * 8); // conflict-free
                #pragma unroll
                for (int p = 0; p < 4; ++p)
                    acc[p] = __builtin_amdgcn_mfma_f32_16x16x32_bf16(a[p][t], b, acc[p], 0, 0, 0);
            }
            const int crow = c_begin + ctile + m16;
            #pragma unroll
            for (int p = 0; p < 4; ++p)
                #pragma unroll
                for (int r = 0; r < 4; ++r) {
                    const bool own = (crow == lab[p][r]);
                    const float sel = own ? INFF : cn2v;
                    rm[p][r] = fminf(rm[p][r], sel + acc[p][r]);
                    dacc[p][r] += own ? acc[p][r] : 0.0f;
                }
        }
        __syncthreads();
    }
    #pragma unroll
    for (int off = 1; off < 16; off <<= 1)
        #pragma unroll
        for (int p = 0; p < 4; ++p)
            #pragma unroll
            for (int r = 0; r < 4; ++r) {
                rm[p][r] = fminf(rm[p][r], __shfl_xor(rm[p][r], off, 64));
                dacc[p][r] += __shfl_xor(dacc[p][r], off, 64);
            }
    if (m16 == 0) {
        float* mv = minval + (size_t)blockIdx.y * Bn;
        float* dv = dotown + (size_t)blockIdx.y * Bn;
        #pragma unroll
        for (int p = 0; p < 4; ++p)
            #pragma unroll
            for (int r = 0; r < 4; ++r) {
                mv[sbase + p * 16 + quad * 4 + r] = rm[p][r];
                dv[sbase + p * 16 + quad * 4 + r] = dacc[p][r];
            }
    }
}

// ---------------- K6: d_p, d_n, softplus, reduce + last-block finalize ----
__global__ __launch_bounds__(256) void k_final(const int* __restrict__ labels,
                                               const int* __restrict__ cnt_i,
                                               const float* __restrict__ cn2x,
                                               const float* __restrict__ minval,
                                               const float* __restrict__ dotown,
                                               const int* __restrict__ epoch,
                                               float* __restrict__ accum,
                                               unsigned* __restrict__ donecnt,
                                               float* __restrict__ out) {
    const int i = blockIdx.x * 256 + threadIdx.x;
    const int lane = threadIdx.x & 63;
    const float temp = fminf(0.3f + 0.02f * (float)(*epoch), 1.0f);
    float m = minval[i];
    float draw = dotown[i];                 // = -2 * f.c_own (one split nonzero)
    #pragma unroll
    for (int k = 1; k < NSPLIT; ++k) {
        m = fminf(m, minval[(size_t)k * Bn + i]);
        draw += dotown[(size_t)k * Bn + i];
    }
    const int l = labels[i];
    const int n = cnt_i[l];
    const float nf = (float)n;
    const float cn2 = cn2x[l];              // finite (n >= 1)
    // d_p from ||f||^2=1, f.s = n*f.c, ||s||^2 = n^2*cn2:
    const float fds = nf * (-0.5f * draw);
    const float fm1 = fmaxf(nf - 1.0f, 1.0f);
    const float fdcp = (fds - 1.0f) / fm1;
    const float cp2 = (nf * nf * cn2 - 2.0f * fds + 1.0f) / (fm1 * fm1);
    const float dp2 = 1.0f - 2.0f * fdcp + cp2;
    const float d_p = sqrtf(fmaxf(dp2, 0.0f) + EPSF);
    const bool finite = (m < 1e37f);
    const float d_n = finite ? sqrtf(fmaxf(1.0f + m, EPSF)) : 0.0f;
    const bool valid = (n > 1) && finite;
    const float x = (d_p - d_n) / temp;
    const float sp = fmaxf(x, 0.0f) + log1pf(expf(-fabsf(x)));
    float ws = valid ? sp : 0.0f, wc = valid ? 1.0f : 0.0f;
    #pragma unroll
    for (int off = 1; off < 64; off <<= 1) {
        ws += __shfl_xor(ws, off, 64);
        wc += __shfl_xor(wc, off, 64);
    }
    if (lane == 0) {
        atomicAdd(&accum[0], ws);
        atomicAdd(&accum[1], wc);
        __threadfence();   // release: my adds visible before donecnt bump
    }
    __syncthreads();
    if (threadIdx.x == 0) {
        const unsigned old = atomicAdd(donecnt, 1u);
        if (old == (unsigned)(gridDim.x - 1)) {   // last block finalizes
            __threadfence();   // acquire
            const float s = __hip_atomic_load(&accum[0], __ATOMIC_RELAXED,
                                              __HIP_MEMORY_SCOPE_AGENT);
            const float c = __hip_atomic_load(&accum[1], __ATOMIC_RELAXED,
                                              __HIP_MEMORY_SCOPE_AGENT);
            out[0] = (c > 0.0f) ? (s / fmaxf(c, 1.0f)) : 0.0f;   // WEIGHT = 1.0
        }
    }
}

// ---------------- launch ---------------------------------------------------
// Graph: 7 nodes: memset(hist), prep, scan, scatter, centseg, main, final.
// (R9-verified best configuration, 161.05us.)
extern "C" void kernel_launch(void* const* d_in, const int* in_sizes, int n_in,
                              void* d_out, int out_size, void* d_ws, size_t ws_size,
                              hipStream_t stream) {
    const float* feat  = (const float*)d_in[0];
    const int* labels  = (const int*)d_in[1];
    const int* epoch   = (const int*)d_in[2];
    float* out = (float*)d_out;
    char* ws = (char*)d_ws;

    size_t off = 0;
    __bf16* fneg     = (__bf16*)(ws + off); off += (size_t)Bn * Dn * 2;     // 16 MiB
    __bf16* centK    = (__bf16*)(ws + off); off += (size_t)Cn * Dn * 2;     //  1 MiB
    float*  cn2x     = (float*)(ws + off);  off += (size_t)Cn * 4;
    int*    hist     = (int*)(ws + off);    off += (size_t)Cn * 4;
    int*    cnt_i    = (int*)(ws + off);    off += (size_t)Cn * 4;
    int*    offs     = (int*)(ws + off);    off += (size_t)Cn * 4;
    int*    offs_wk  = (int*)(ws + off);    off += (size_t)Cn * 4;
    int*    order    = (int*)(ws + off);    off += (size_t)Bn * 4;
    float*  minval   = (float*)(ws + off);  off += (size_t)NSPLIT * Bn * 4;
    float*  dotown   = (float*)(ws + off);  off += (size_t)NSPLIT * Bn * 4;
    float*  accum    = (float*)(ws + off);  off += 2 * 4;
    unsigned* donecnt = (unsigned*)(ws + off); off += 4;

    (void)hipMemsetAsync(hist, 0, (size_t)Cn * sizeof(int), stream);

    k_prep<<<Bn / 4, 256, 0, stream>>>(feat, labels, fneg, hist);
    k_scan<<<1, 256, 0, stream>>>(hist, cnt_i, offs, offs_wk, accum, donecnt);
    k_scatter<<<Bn / 256, 256, 0, stream>>>(labels, offs_wk, order);
    k_centseg<<<Cn / 4, 256, 0, stream>>>(fneg, order, offs, cnt_i, centK, cn2x);
    dim3 g5(Bn / 256, NSPLIT);
    k_main<<<g5, 256, 0, stream>>>(fneg, labels, centK, cn2x, minval, dotown);
    k_final<<<Bn / 256, 256, 0, stream>>>(labels, cnt_i, cn2x, minval, dotown,
                                          epoch, accum, donecnt, out);
}